// Round 8
// baseline (7725.381 us; speedup 1.0000x reference)
//
#include <hip/hip_runtime.h>

// ---- problem constants -----------------------------------------------------
#define BTOT   4096      // batch
#define TWARM  64        // warm timesteps
#define FIN    64        // input features
#define UDIM   256       // hidden units
#define ZDIM   1024      // 4*U gate pre-activations
#define KDIM   320       // FIN + UDIM
#define OSTEPS 24
#define OCOLS  65        // dense out dim (F+1)
#define BR     64        // batch rows per block -> 64 blocks (R8: 4x work/W-byte)
#define NB     (BTOT / BR)
#define ASTR   328       // LDS A row stride in bf16 (320+8; rows 2-way banks, free)
#define NTHR   512       // 8 waves
#define NWAVE  8
#define MT     4         // row-tiles per wave (rows = m*16 + ...)
#define RING   4         // per-wave LDS ring slots (frag = 2 KB)
#define NFRAG  80        // kt(10) x ct(8); ct = g*2+ut; wave owns u[wv*32..+32)
// R8 theory: chip-wide L2-miss path (~2 TB/s, R7 counters) is the binding
// constraint; W bytes/CU/step are fixed, so cut ACTIVE CUs 4x while giving
// each W frag 4x the MFMAs (MT=4). 8-wave blocks allow 256 VGPR/wave.
// Wp layout: frag-linear. ((kt*8+ct)*8 + wv)*1024 shorts:
//   [0,512) hi per lane (lane*8 shorts = 16 B), [512,1024) lo residual.
// Dp layout (dense): (ct*8+kt)*1024 + lcol*64 + lrow*16 + hl*8 + j (ct 0..4)

typedef short bf16x8 __attribute__((ext_vector_type(8)));
typedef short s16x4  __attribute__((ext_vector_type(4)));
typedef float f32x4  __attribute__((ext_vector_type(4)));

static __device__ __forceinline__ short f2bf(float x) {  // RNE f32 -> bf16 bits
  unsigned u = __float_as_uint(x);
  return (short)((u + 0x7fffu + ((u >> 16) & 1u)) >> 16);
}
static __device__ __forceinline__ float bf2f(short h) {
  return __uint_as_float(((unsigned)(unsigned short)h) << 16);
}
static __device__ __forceinline__ float sigm(float x) {
  return 1.0f / (1.0f + __expf(-x));
}
static __device__ __forceinline__ float tanh_(float x) {
  return 2.0f / (1.0f + __expf(-2.0f * x)) - 1.0f;
}
// async global->LDS, 16B per lane; lds dest = wave-uniform base + lane*16
static __device__ __forceinline__ void gload_lds16(const short* g, short* l) {
  __builtin_amdgcn_global_load_lds(
      (const __attribute__((address_space(1))) void*)g,
      (__attribute__((address_space(3))) void*)l, 16, 0, 0);
}

// ---- weight repack into frag-linear DMA order -------------------------------
__global__ void pack_w_kernel(const float* __restrict__ kern,
                              const float* __restrict__ rec,
                              short* __restrict__ Wp) {
  const int col = blockIdx.x;   // 0..1023 (zcol)
  const int k   = threadIdx.x;  // 0..319
  const float w = (k < FIN) ? kern[k * ZDIM + col] : rec[(k - FIN) * ZDIM + col];
  const short hi = f2bf(w);
  const int g   = col >> 8;
  const int u   = col & 255;
  const int wvp = u >> 5;
  const int ut  = (u >> 4) & 1;
  const int lc  = u & 15;
  const int ct  = g * 2 + ut;
  const int kt  = k >> 5;
  const int lr  = (k >> 3) & 3;
  const int j   = k & 7;
  const int base = ((kt * 8 + ct) * 8 + wvp) * 1024 + (lr * 16 + lc) * 8 + j;
  Wp[base]       = hi;
  Wp[base + 512] = f2bf(w - bf2f(hi));
}

__global__ void pack_dw_kernel(const float* __restrict__ dw,
                               short* __restrict__ Dp) {
  const int col = blockIdx.x;   // 0..79 (>=65 zero-padded)
  const int k   = threadIdx.x;  // 0..255
  const float w = (col < OCOLS) ? dw[k * OCOLS + col] : 0.0f;
  const short hi = f2bf(w);
  const int ct = col >> 4;
  const int lc = col & 15;
  const int kt = k >> 5;
  const int lr = (k >> 3) & 3;
  const int j  = k & 7;
  const int base = (ct * 8 + kt) * 1024 + lc * 64 + lr * 16 + j;
  Dp[base]     = hi;
  Dp[base + 8] = f2bf(w - bf2f(hi));
}

// ---- persistent LSTM + AR kernel -------------------------------------------
__global__ __launch_bounds__(NTHR, 2) void lstm_ar_kernel(
    const float* __restrict__ inputs, const float* __restrict__ bias,
    const float* __restrict__ dense_b, const short* __restrict__ Wp,
    const short* __restrict__ Dp, float* __restrict__ out) {
  __shared__ short Ah[BR * ASTR];            // A = [x(0:64)|h(64:320)] bf16 hi
  __shared__ short Al[BR * ASTR];            // bf16 lo residual (84 KB both)
  __shared__ short Wring[NWAVE * RING * 1024]; // per-wave 4-slot ring (64 KB)

  const int tid  = (int)threadIdx.x;
  const int wv   = tid >> 6;        // wave 0..7; owns u in [wv*32, wv*32+32)
  const int lane = tid & 63;
  const int lrow = lane >> 4;       // k-group 0..3
  const int lcol = lane & 15;
  const int b0   = (int)blockIdx.x * BR;

  float bz[2][4];
#pragma unroll
  for (int ut = 0; ut < 2; ++ut)
#pragma unroll
    for (int g = 0; g < 4; ++g)
      bz[ut][g] = bias[g * UDIM + wv * 32 + ut * 16 + lcol];

  // cell state, C/D layout: row = m*16+lrow*4+q, u = wv*32+ut*16+lcol
  float cst[MT][2][4] = {{{0.0f}}};

  // issue one 2 KB frag (hi 1 KB + lo 1 KB) into this wave's ring slot
  auto issue_frag = [&](int f, int slot) {
    const short* gs = Wp + (f * 8 + wv) * 1024 + lane * 8;  // per-lane 16 B
    short* ls = &Wring[(wv * RING + slot) * 1024];          // wave-uniform
    gload_lds16(gs, ls);
    gload_lds16(gs + 512, ls + 512);
  };

  // stage x_t: 64 rows x 16 float4 = 1024 loads, 2 per thread
  auto stage_x = [&](int t) {
#pragma unroll
    for (int i = 0; i < 2; ++i) {
      const int idx = tid + i * NTHR;
      const int r   = idx >> 4;
      const int c4  = (idx & 15) << 2;
      const float4 v = *reinterpret_cast<const float4*>(
          inputs + (size_t)(b0 + r) * (TWARM * FIN) + (size_t)t * FIN + c4);
      s16x4 hi, lo;
      hi[0] = f2bf(v.x); lo[0] = f2bf(v.x - bf2f(hi[0]));
      hi[1] = f2bf(v.y); lo[1] = f2bf(v.y - bf2f(hi[1]));
      hi[2] = f2bf(v.z); lo[2] = f2bf(v.z - bf2f(hi[2]));
      hi[3] = f2bf(v.w); lo[3] = f2bf(v.w - bf2f(hi[3]));
      *reinterpret_cast<s16x4*>(&Ah[r * ASTR + c4]) = hi;
      *reinterpret_cast<s16x4*>(&Al[r * ASTR + c4]) = lo;
    }
  };

  // one LSTM step. Per wave: 80 frags x {vmcnt, 2 ds_read_b128, lgkm(0),
  // reissue, 12 MFMA}; A frags reloaded per kt. No barriers in frag loop.
  auto lstm_step = [&]() {
    f32x4 acc[MT][2][4];
#pragma unroll
    for (int m = 0; m < MT; ++m)
#pragma unroll
      for (int ut = 0; ut < 2; ++ut)
#pragma unroll
        for (int g = 0; g < 4; ++g) {
          acc[m][ut][g][0] = bz[ut][g]; acc[m][ut][g][1] = bz[ut][g];
          acc[m][ut][g][2] = bz[ut][g]; acc[m][ut][g][3] = bz[ut][g];
        }
    issue_frag(0, 0); issue_frag(1, 1); issue_frag(2, 2); issue_frag(3, 3);
#pragma unroll
    for (int kt = 0; kt < 10; ++kt) {
      bf16x8 ah[MT], al[MT];
#pragma unroll
      for (int m = 0; m < MT; ++m) {
        const int aoff = (m * 16 + lcol) * ASTR + kt * 32 + lrow * 8;
        ah[m] = *reinterpret_cast<const bf16x8*>(&Ah[aoff]);
        al[m] = *reinterpret_cast<const bf16x8*>(&Al[aoff]);
      }
#pragma unroll
      for (int ct = 0; ct < 8; ++ct) {
        const int f = kt * 8 + ct;
        const int slot = f & (RING - 1);
        const int g = ct >> 1, ut = ct & 1;
        // frag f resident when <= 2*(frags still in flight beyond f) remain
        if (f <= NFRAG - 4)      asm volatile("s_waitcnt vmcnt(6)" ::: "memory");
        else if (f == NFRAG - 3) asm volatile("s_waitcnt vmcnt(4)" ::: "memory");
        else if (f == NFRAG - 2) asm volatile("s_waitcnt vmcnt(2)" ::: "memory");
        else                     asm volatile("s_waitcnt vmcnt(0)" ::: "memory");
        const short* wb = &Wring[(wv * RING + slot) * 1024 + lane * 8];
        const bf16x8 wh = *reinterpret_cast<const bf16x8*>(wb);
        const bf16x8 wl = *reinterpret_cast<const bf16x8*>(wb + 512);
        // ds_reads of this slot retired before its DMA reissue (ring safety)
        asm volatile("s_waitcnt lgkmcnt(0)" ::: "memory");
        if (f + RING < NFRAG) issue_frag(f + RING, slot);
#pragma unroll
        for (int m = 0; m < MT; ++m) {
          acc[m][ut][g] = __builtin_amdgcn_mfma_f32_16x16x32_bf16(ah[m], wh, acc[m][ut][g], 0, 0, 0);
          acc[m][ut][g] = __builtin_amdgcn_mfma_f32_16x16x32_bf16(al[m], wh, acc[m][ut][g], 0, 0, 0);
          acc[m][ut][g] = __builtin_amdgcn_mfma_f32_16x16x32_bf16(ah[m], wl, acc[m][ut][g], 0, 0, 0);
        }
      }
    }
    __syncthreads();  // all waves done reading A before h is overwritten
#pragma unroll
    for (int m = 0; m < MT; ++m)
#pragma unroll
      for (int ut = 0; ut < 2; ++ut)
#pragma unroll
        for (int q = 0; q < 4; ++q) {
          const float iv = sigm(acc[m][ut][0][q]);
          const float fv = sigm(acc[m][ut][1][q]);
          const float gv = tanh_(acc[m][ut][2][q]);
          const float ov = sigm(acc[m][ut][3][q]);
          const float c  = fv * cst[m][ut][q] + iv * gv;
          cst[m][ut][q]  = c;
          const float h  = ov * tanh_(c);
          const int row  = m * 16 + lrow * 4 + q;
          const int u    = wv * 32 + ut * 16 + lcol;
          const short hi = f2bf(h);
          Ah[row * ASTR + FIN + u] = hi;
          Al[row * ASTR + FIN + u] = f2bf(h - bf2f(hi));
        }
  };

  // dense task τ = m*5+ct: pred tile (rows m*16.., cols ct*16..). 20 tasks.
  auto dense_task = [&](int tau, int s) {
    const int m  = tau / 5;
    const int ct = tau % 5;
    const int col = ct * 16 + lcol;
    const float pb = (col < OCOLS) ? dense_b[col] : 0.0f;
    f32x4 p; p[0] = pb; p[1] = pb; p[2] = pb; p[3] = pb;
    const int laneoff = lcol * 64 + lrow * 16;
#pragma unroll
    for (int kt = 0; kt < 8; ++kt) {
      const int aoff = (m * 16 + lcol) * ASTR + FIN + kt * 32 + lrow * 8;
      const bf16x8 ah = *reinterpret_cast<const bf16x8*>(&Ah[aoff]);
      const bf16x8 al = *reinterpret_cast<const bf16x8*>(&Al[aoff]);
      const int doff = (ct * 8 + kt) * 1024 + laneoff;
      const bf16x8 dh = *reinterpret_cast<const bf16x8*>(Dp + doff);
      const bf16x8 dl = *reinterpret_cast<const bf16x8*>(Dp + doff + 8);
      p = __builtin_amdgcn_mfma_f32_16x16x32_bf16(ah, dh, p, 0, 0, 0);
      p = __builtin_amdgcn_mfma_f32_16x16x32_bf16(al, dh, p, 0, 0, 0);
      p = __builtin_amdgcn_mfma_f32_16x16x32_bf16(ah, dl, p, 0, 0, 0);
    }
    if (ct < 4) {        // x_next = pred[:, 0:64]
#pragma unroll
      for (int q = 0; q < 4; ++q) {
        const float v  = p[q];
        const int row  = m * 16 + lrow * 4 + q;
        const short hi = f2bf(v);
        Ah[row * ASTR + col] = hi;
        Al[row * ASTR + col] = f2bf(v - bf2f(hi));
      }
    } else if (lcol == 0) {  // col 64 = the output column
#pragma unroll
      for (int q = 0; q < 4; ++q)
        out[(size_t)(b0 + m * 16 + lrow * 4 + q) * OSTEPS + s] = p[q];
    }
  };

  // init: zero A (h0 = 0), stage x_0
  for (int i = tid; i < BR * ASTR; i += NTHR) { Ah[i] = 0; Al[i] = 0; }
  __syncthreads();
  stage_x(0);
  __syncthreads();

  // ---- warm phase ----
#pragma unroll 1
  for (int t = 0; t < TWARM; ++t) {
    lstm_step();
    if (t + 1 < TWARM) stage_x(t + 1);   // x region disjoint from h region
    __syncthreads();
  }

  // ---- autoregressive phase ----
#pragma unroll 1
  for (int s = 0; s < OSTEPS; ++s) {
    dense_task(wv, s);
    dense_task(wv + 8, s);
    if (wv < 4) dense_task(wv + 16, s);
    __syncthreads();
    if (s + 1 < OSTEPS) {
      lstm_step();
      __syncthreads();
    }
  }
}

// ---- launch ---------------------------------------------------------------
extern "C" void kernel_launch(void* const* d_in, const int* in_sizes, int n_in,
                              void* d_out, int out_size, void* d_ws, size_t ws_size,
                              hipStream_t stream) {
  (void)in_sizes; (void)n_in; (void)out_size; (void)ws_size;
  const float* inputs = (const float*)d_in[0];
  const float* kern   = (const float*)d_in[1];
  const float* rec    = (const float*)d_in[2];
  const float* bias   = (const float*)d_in[3];
  const float* dw     = (const float*)d_in[4];
  const float* db     = (const float*)d_in[5];
  float* out = (float*)d_out;

  short* Wp = (short*)d_ws;              // 80 frag-groups * 8 waves * 1024 shorts = 1.31 MB
  short* Dp = Wp + NFRAG * 8 * 1024;     // 5*8*1024 shorts = 82 KB

  hipLaunchKernelGGL(pack_w_kernel,  dim3(ZDIM), dim3(KDIM), 0, stream, kern, rec, Wp);
  hipLaunchKernelGGL(pack_dw_kernel, dim3(80),   dim3(UDIM), 0, stream, dw, Dp);
  hipLaunchKernelGGL(lstm_ar_kernel, dim3(NB), dim3(NTHR), 0, stream,
                     inputs, bias, db, Wp, Dp, out);
}